// Round 8
// baseline (173.012 us; speedup 1.0000x reference)
//
#include <hip/hip_runtime.h>
#include <math.h>

#define N_MELS   128
#define N_FFT    2048
#define HOP      512
#define BATCH    8
#define S_LEN    661500
#define CH       2
#define T_FRAMES 1292            // 1 + S_LEN/HOP
#define NBINS    1025            // 1 + N_FFT/2

#define ANG 0.003067961575771282f   // 2*pi/2048

// d_ws layout (byte offsets)
#define WS_WIN     0        // float[2048]   hann window
#define WS_TW      8192     // float2[2048]  W_2048^j
#define WS_RANGES  24576    // int[256]      per-mel [start,end)
#define WS_TWS     25600    // float2[3][7][256] stage twiddles W^{(k+1)*e1(tid)}

#define PW_OFF     1056     // float plane stride: pw[c*1056 + f]

__device__ __forceinline__ float2 cadd(float2 a, float2 b){ return make_float2(a.x+b.x, a.y+b.y); }
__device__ __forceinline__ float2 csub(float2 a, float2 b){ return make_float2(a.x-b.x, a.y-b.y); }
__device__ __forceinline__ float2 cmul(float2 a, float2 b){ return make_float2(a.x*b.x - a.y*b.y, a.x*b.y + a.y*b.x); }
__device__ __forceinline__ float2 cnegi(float2 z){ return make_float2(z.y, -z.x); }   // -i*z

// Half-buffer padded layout: element e (in [0,1024)) lives at Z[e + 2*(e>>4)].
#define ZPAD 1152            // 1024 + 2*64 float2 = 9216 B

// radix-8 DIF butterfly: b[k] = sum_j a[j] * W8^{jk}, W8 = exp(-i*pi/4)
__device__ __forceinline__ void bfly8(const float2* a, float2* b) {
    const float C = 0.70710678118654752f;
    float2 e0=cadd(a[0],a[4]), e1=cadd(a[1],a[5]), e2=cadd(a[2],a[6]), e3=cadd(a[3],a[7]);
    float2 o0=csub(a[0],a[4]), o1=csub(a[1],a[5]), o2=csub(a[2],a[6]), o3=csub(a[3],a[7]);
    float2 t1 = make_float2(C*(o1.x+o1.y), C*(o1.y-o1.x));      // o1*W8^1
    float2 t2 = make_float2(o2.y, -o2.x);                        // o2*W8^2 (-i)
    float2 t3 = make_float2(C*(o3.y-o3.x), -C*(o3.x+o3.y));      // o3*W8^3
    {
        float2 s0=cadd(e0,e2), d0=csub(e0,e2);
        float2 s1=cadd(e1,e3), d1=csub(e1,e3);
        b[0]=cadd(s0,s1); b[4]=csub(s0,s1);
        b[2]=cadd(d0,cnegi(d1)); b[6]=csub(d0,cnegi(d1));
    }
    {
        float2 s0=cadd(o0,t2), d0=csub(o0,t2);
        float2 s1=cadd(t1,t3), d1=csub(t1,t3);
        b[1]=cadd(s0,s1); b[5]=csub(s0,s1);
        b[3]=cadd(d0,cnegi(d1)); b[7]=csub(d0,cnegi(d1));
    }
}

// apply table twiddles tw7[k-1] to bq[k] (k=1..7)
__device__ __forceinline__ void twid(const float2* bq, const float2* tw7, float2* w8) {
    w8[0] = bq[0];
    #pragma unroll
    for (int k = 1; k < 8; ++k) w8[k] = cmul(tw7[k-1], bq[k]);
}

// two-channel untangle: (|A|^2, |B|^2) for Zf, Zm = Z[N-f]
__device__ __forceinline__ float2 upair(float2 Zf, float2 Zm) {
    float br = Zm.x, bi = -Zm.y;
    float e0 = Zf.x + br, e1 = Zf.y + bi;
    float o0 = Zf.y - bi, o1 = Zf.x - br;
    return make_float2(0.25f*(e0*e0 + e1*e1), 0.25f*(o0*o0 + o1*o1));
}

// --- setup: blocks 0..7 tables, 8..135 mel ranges, 136..156 stage twiddles ---
__global__ __launch_bounds__(256) void setup_kernel(
        const float* __restrict__ fb, float* __restrict__ ws) {
    int blk = blockIdx.x;
    if (blk < 8) {
        int i = blk * 256 + threadIdx.x;
        float*  win = ws;
        float2* tw  = (float2*)((char*)ws + WS_TW);
        win[i] = 0.5f - 0.5f * cosf(ANG * (float)i);
        float sn, cs; sincosf(-ANG * (float)i, &sn, &cs);
        tw[i] = make_float2(cs, sn);
    } else if (blk < 136) {
        int m = blk - 8;
        int lane = threadIdx.x;
        if (lane < 64) {
            int* ranges = (int*)((char*)ws + WS_RANGES);
            const float* row = fb + m * NBINS;
            int s = NBINS, e = -1;
            for (int f = lane; f < NBINS; f += 64) {
                if (row[f] != 0.0f) { if (f < s) s = f; if (f > e) e = f; }
            }
            #pragma unroll
            for (int o = 32; o; o >>= 1) {
                s = min(s, __shfl_xor(s, o));
                e = max(e, __shfl_xor(e, o));
            }
            if (lane == 0) {
                ranges[2*m]   = (e < 0) ? 0 : s;
                ranges[2*m+1] = e + 1;
            }
        }
    } else {
        int idx = (blk - 136) * 256 + threadIdx.x;    // [0, 5376)
        int s  = idx / 1792;
        int r  = idx - s * 1792;
        int k  = r >> 8;
        int tt = r & 255;
        int e1 = (s == 0) ? tt : (s == 1) ? (tt & ~7) : (tt & ~63);
        float sn, cs; sincosf(-ANG * (float)((k + 1) * e1), &sn, &cs);
        ((float2*)((char*)ws + WS_TWS))[idx] = make_float2(cs, sn);
    }
}

// --- main: register radix-8 FFT (2048 = 8*8*8*4), half-buffer exchanges ---
__global__ __launch_bounds__(256, 8) void mel_spec_kernel(
        const float* __restrict__ x, const float* __restrict__ fb,
        const float* __restrict__ ws, float* __restrict__ out) {
    __shared__ float4 Zq[ZPAD/2];            // 9216 B total
    float2* Z   = (float2*)Zq;
    float*  pwf = (float*)Zq;                // planes: [0,1025) and [1056,2081)

    const float*  win    = ws;
    const int*    ranges = (const int*)((const char*)ws + WS_RANGES);
    const float2* tws    = (const float2*)((const char*)ws + WS_TWS);

    const int tid = threadIdx.x;
    const int bid = blockIdx.x;
    const int b   = bid & 7;          // XCD-contiguous: one batch item per XCD
    const int t   = bid >> 3;

    const float2* xb = (const float2*)x + (size_t)b * S_LEN;
    const int tb = t*HOP - (N_FFT/2);

    float2 r[8], bq[8], w8[8];
    const int rb = tid + 2*(tid>>4);   // OFF(tid): read base, stride 288 per k

    // Stage-1 twiddles: issue loads before the input loads' consumers.
    float2 tA[7];
    #pragma unroll
    for (int k = 0; k < 7; ++k) tA[k] = tws[k*256 + tid];

    // ---- Input: r[k] = z[tid + 256k] windowed (coalesced global loads).
    if (tb >= 0 && tb + (N_FFT - 1) < S_LEN) {
        #pragma unroll
        for (int k = 0; k < 8; ++k) {
            int n = tid + 256*k;
            float2 v = xb[tb + n];
            float  w = win[n];
            r[k] = make_float2(v.x*w, v.y*w);
        }
    } else {
        #pragma unroll
        for (int k = 0; k < 8; ++k) {
            int n  = tid + 256*k;
            int s0 = tb + n;
            if (s0 < 0) s0 = -s0; else if (s0 >= S_LEN) s0 = 2*S_LEN - 2 - s0;
            float2 v = xb[s0];
            float  w = win[n];
            r[k] = make_float2(v.x*w, v.y*w);
        }
    }

    // ======== Stage 1: radix-8, s=1. Outputs e = 8*tid + k (contiguous -> b128).
    bfly8(r, bq);
    twid(bq, tA, w8);
    {
        if (tid < 128) {
            int f4 = 4*tid + (tid>>1);
            #pragma unroll
            for (int j = 0; j < 4; ++j)
                Zq[f4+j] = make_float4(w8[2*j].x, w8[2*j].y, w8[2*j+1].x, w8[2*j+1].y);
        }
        __syncthreads();
        r[0]=Z[rb]; r[1]=Z[rb+288]; r[2]=Z[rb+576]; r[3]=Z[rb+864];
        __syncthreads();
        if (tid >= 128) {
            int tt = tid - 128;
            int f4 = 4*tt + (tt>>1);
            #pragma unroll
            for (int j = 0; j < 4; ++j)
                Zq[f4+j] = make_float4(w8[2*j].x, w8[2*j].y, w8[2*j+1].x, w8[2*j+1].y);
        }
        __syncthreads();
        r[4]=Z[rb]; r[5]=Z[rb+288]; r[6]=Z[rb+576]; r[7]=Z[rb+864];
        __syncthreads();
    }

    // Stage-2 twiddles (issued ~one phase ahead of use).
    float2 tB[7];
    #pragma unroll
    for (int k = 0; k < 7; ++k) tB[k] = tws[1792 + k*256 + tid];

    // ======== Stage 2: radix-8, s=8. Outputs e = q + 64a + 8k (q=tid&7, a=tid>>3).
    bfly8(r, bq);
    twid(bq, tB, w8);
    {
        int q = tid & 7, a = tid >> 3;
        if (tid < 128) {
            int base = q + 72*a;
            #pragma unroll
            for (int k = 0; k < 8; ++k) Z[base + 8*k + 2*(k>>1)] = w8[k];
        }
        __syncthreads();
        r[0]=Z[rb]; r[1]=Z[rb+288]; r[2]=Z[rb+576]; r[3]=Z[rb+864];
        __syncthreads();
        if (tid >= 128) {
            int base = q + 72*(a-16);
            #pragma unroll
            for (int k = 0; k < 8; ++k) Z[base + 8*k + 2*(k>>1)] = w8[k];
        }
        __syncthreads();
        r[4]=Z[rb]; r[5]=Z[rb+288]; r[6]=Z[rb+576]; r[7]=Z[rb+864];
        __syncthreads();
    }

    // Stage-3 twiddles.
    float2 tC[7];
    #pragma unroll
    for (int k = 0; k < 7; ++k) tC[k] = tws[3584 + k*256 + tid];

    // ======== Stage 3: radix-8, s=64. Outputs e = q + 512a + 64k (q=tid&63, a=tid>>6).
    bfly8(r, bq);
    twid(bq, tC, w8);
    // Stage-4 butterfly pair: b1 = tid, b2 = 512-tid (tid=0 -> {0,256}).
    const int b1 = tid;
    const int b2 = (tid == 0) ? 256 : 512 - tid;
    const int rb1 = b1 + 2*(b1>>4);   // OFF(b1);  OFF(b1+512) = rb1+576
    const int rb2 = b2 + 2*(b2>>4);
    float2 A1[4], A2[4];
    {
        int q = tid & 63, a = tid >> 6;
        int qo = q + 2*(q>>4);
        if (tid < 128) {
            int base = qo + 576*a;                 // a in {0,1}
            #pragma unroll
            for (int k = 0; k < 8; ++k) Z[base + 72*k] = w8[k];
        }
        __syncthreads();
        A1[0]=Z[rb1]; A1[1]=Z[rb1+576]; A2[0]=Z[rb2]; A2[1]=Z[rb2+576];
        __syncthreads();
        if (tid >= 128) {
            int base = qo + 576*(a-2);             // a in {2,3}
            #pragma unroll
            for (int k = 0; k < 8; ++k) Z[base + 72*k] = w8[k];
        }
        __syncthreads();
        A1[2]=Z[rb1]; A1[3]=Z[rb1+576]; A2[2]=Z[rb2]; A2[3]=Z[rb2+576];
        __syncthreads();
    }

    // ======== Stage 4 (radix-4, s=512, twiddle-free) in registers.
    float2 O1[4], O2[4];
    {
        float2 apc=cadd(A1[0],A1[2]), amc=csub(A1[0],A1[2]);
        float2 bpd=cadd(A1[1],A1[3]), bmd=csub(A1[1],A1[3]);
        O1[0]=cadd(apc,bpd); O1[1]=cadd(amc,cnegi(bmd));
        O1[2]=csub(apc,bpd); O1[3]=csub(amc,cnegi(bmd));
    }
    {
        float2 apc=cadd(A2[0],A2[2]), amc=csub(A2[0],A2[2]);
        float2 bpd=cadd(A2[1],A2[3]), bmd=csub(A2[1],A2[3]);
        O2[0]=cadd(apc,bpd); O2[1]=cadd(amc,cnegi(bmd));
        O2[2]=csub(apc,bpd); O2[3]=csub(amc,cnegi(bmd));
    }

    // ======== Untangle in registers -> pw planes (aliases Z; reads fenced above).
    if (tid == 0) {
        float2 p;
        p = upair(O1[0], O1[0]); pwf[0]    = p.x; pwf[PW_OFF+0]    = p.y;
        p = upair(O1[1], O1[3]); pwf[512]  = p.x; pwf[PW_OFF+512]  = p.y;
        p = upair(O1[2], O1[2]); pwf[1024] = p.x; pwf[PW_OFF+1024] = p.y;
        p = upair(O2[0], O2[3]); pwf[256]  = p.x; pwf[PW_OFF+256]  = p.y;
        p = upair(O2[1], O2[2]); pwf[768]  = p.x; pwf[PW_OFF+768]  = p.y;
    } else {
        float2 p;
        p = upair(O1[0], O2[3]); pwf[tid]      = p.x; pwf[PW_OFF+tid]      = p.y;
        p = upair(O1[1], O2[2]); pwf[tid+512]  = p.x; pwf[PW_OFF+tid+512]  = p.y;
        p = upair(O2[0], O1[3]); pwf[512-tid]  = p.x; pwf[PW_OFF+512-tid]  = p.y;
        p = upair(O2[1], O1[2]); pwf[1024-tid] = p.x; pwf[PW_OFF+1024-tid] = p.y;
    }
    __syncthreads();

    // ======== Sparse mel projection: (m,c) = (tid>>1, tid&1), paired b64 reads.
    {
        int m = tid >> 1;
        int c = tid & 1;
        int s0 = ranges[2*m];
        int e0 = ranges[2*m+1];
        const float* row = fb + m * NBINS;
        const float* pwc = pwf + c * PW_OFF;
        float acc = 0.0f;
        int f = s0 & ~1;                 // row[s0-1] == 0 when s0 odd (outside span)
        for (; f + 1 < e0; f += 2) {
            float2 p = *(const float2*)(pwc + f);
            acc += row[f] * p.x + row[f+1] * p.y;
        }
        if (f < e0) acc += row[f] * pwc[f];
        out[(((size_t)b * N_MELS + m) * T_FRAMES + t) * CH + c] = acc;
    }
}

extern "C" void kernel_launch(void* const* d_in, const int* in_sizes, int n_in,
                              void* d_out, int out_size, void* d_ws, size_t ws_size,
                              hipStream_t stream) {
    const float* x  = (const float*)d_in[0];
    const float* fb = (const float*)d_in[1];
    float* out = (float*)d_out;
    float* ws  = (float*)d_ws;

    setup_kernel<<<157, 256, 0, stream>>>(fb, ws);
    mel_spec_kernel<<<BATCH * T_FRAMES, 256, 0, stream>>>(x, fb, ws, out);
}

// Round 9
// 153.435 us; speedup vs baseline: 1.1276x; 1.1276x over previous
//
#include <hip/hip_runtime.h>
#include <math.h>

#define N_MELS   128
#define N_FFT    2048
#define HOP      512
#define BATCH    8
#define S_LEN    661500
#define CH       2
#define T_FRAMES 1292            // 1 + S_LEN/HOP
#define NBINS    1025            // 1 + N_FFT/2

#define ANG 0.003067961575771282f   // 2*pi/2048

// d_ws layout (byte offsets)
#define WS_WIN     0        // float[2048]   hann window
#define WS_TW      8192     // float2[2048]  W_2048^j
#define WS_WBEG    24576    // int[128]      4-aligned start bin per mel
#define WS_WTAB    25600    // float[128*64] dense zero-padded mel weights

#define PW_OFF     1056     // float plane stride: pw[c*1056 + f]

__device__ __forceinline__ float2 cadd(float2 a, float2 b){ return make_float2(a.x+b.x, a.y+b.y); }
__device__ __forceinline__ float2 csub(float2 a, float2 b){ return make_float2(a.x-b.x, a.y-b.y); }
__device__ __forceinline__ float2 cmul(float2 a, float2 b){ return make_float2(a.x*b.x - a.y*b.y, a.x*b.y + a.y*b.x); }
__device__ __forceinline__ float2 cnegi(float2 z){ return make_float2(z.y, -z.x); }   // -i*z

// Half-buffer padded layout: element e (in [0,1024)) lives at Z[e + 2*(e>>4)].
#define ZPAD 1152            // 1024 + 2*64 float2 = 9216 B

// radix-8 DIF butterfly: b[k] = sum_j a[j] * W8^{jk}, W8 = exp(-i*pi/4)
__device__ __forceinline__ void bfly8(const float2* a, float2* b) {
    const float C = 0.70710678118654752f;
    float2 e0=cadd(a[0],a[4]), e1=cadd(a[1],a[5]), e2=cadd(a[2],a[6]), e3=cadd(a[3],a[7]);
    float2 o0=csub(a[0],a[4]), o1=csub(a[1],a[5]), o2=csub(a[2],a[6]), o3=csub(a[3],a[7]);
    float2 t1 = make_float2(C*(o1.x+o1.y), C*(o1.y-o1.x));      // o1*W8^1
    float2 t2 = make_float2(o2.y, -o2.x);                        // o2*W8^2 (-i)
    float2 t3 = make_float2(C*(o3.y-o3.x), -C*(o3.x+o3.y));      // o3*W8^3
    {
        float2 s0=cadd(e0,e2), d0=csub(e0,e2);
        float2 s1=cadd(e1,e3), d1=csub(e1,e3);
        b[0]=cadd(s0,s1); b[4]=csub(s0,s1);
        b[2]=cadd(d0,cnegi(d1)); b[6]=csub(d0,cnegi(d1));
    }
    {
        float2 s0=cadd(o0,t2), d0=csub(o0,t2);
        float2 s1=cadd(t1,t3), d1=csub(t1,t3);
        b[1]=cadd(s0,s1); b[5]=csub(s0,s1);
        b[3]=cadd(d0,cnegi(d1)); b[7]=csub(d0,cnegi(d1));
    }
}

// incremental twiddle chain: w8[k] = bq[k] * w1^k (VALU-only, overlaps with
// other waves; R8 showed table loads on the critical path regress)
__device__ __forceinline__ void twiddle8(const float2* bq, float2 w1, float2* w8) {
    w8[0] = bq[0];
    float2 wk = w1;
    #pragma unroll
    for (int k = 1; k < 8; ++k) { w8[k] = cmul(wk, bq[k]); wk = cmul(wk, w1); }
}

// two-channel untangle: (|A|^2, |B|^2) for Zf, Zm = Z[N-f]
__device__ __forceinline__ float2 upair(float2 Zf, float2 Zm) {
    float br = Zm.x, bi = -Zm.y;
    float e0 = Zf.x + br, e1 = Zf.y + bi;
    float o0 = Zf.y - bi, o1 = Zf.x - br;
    return make_float2(0.25f*(e0*e0 + e1*e1), 0.25f*(o0*o0 + o1*o1));
}

// --- setup: blocks 0..7 build tables; blocks 8..135: mel weight rows ---
__global__ __launch_bounds__(256) void setup_kernel(
        const float* __restrict__ fb, float* __restrict__ ws) {
    int blk = blockIdx.x;
    if (blk < 8) {
        int i = blk * 256 + threadIdx.x;
        float*  win = ws;
        float2* tw  = (float2*)((char*)ws + WS_TW);
        win[i] = 0.5f - 0.5f * cosf(ANG * (float)i);
        float sn, cs; sincosf(-ANG * (float)i, &sn, &cs);
        tw[i] = make_float2(cs, sn);
    } else {
        int m = blk - 8;
        int lane = threadIdx.x;
        if (lane < 64) {
            int*   wbeg = (int*)((char*)ws + WS_WBEG);
            float* wtab = (float*)((char*)ws + WS_WTAB);
            const float* row = fb + m * NBINS;
            int s = NBINS;
            for (int f = lane; f < NBINS; f += 64)
                if (row[f] != 0.0f && f < s) s = f;
            #pragma unroll
            for (int o = 32; o; o >>= 1) s = min(s, __shfl_xor(s, o));
            int a0 = s & ~3;              // 4-aligned start; slaney span<=54+3<64
            if (a0 > NBINS - 1) a0 = (NBINS - 1) & ~3;
            if (lane == 0) wbeg[m] = a0;
            int f = a0 + lane;
            wtab[(m << 6) + lane] = (f < NBINS) ? row[f] : 0.0f;
        }
    }
}

// --- main: register radix-8 FFT (2048 = 8*8*8*4), half-buffer exchanges ---
__global__ __launch_bounds__(256, 8) void mel_spec_kernel(
        const float* __restrict__ x, const float* __restrict__ fb,
        const float* __restrict__ ws, float* __restrict__ out) {
    __shared__ float4 Zq[ZPAD/2];            // 9216 B total
    float2* Z   = (float2*)Zq;
    float*  pwf = (float*)Zq;                // planes: [0,1025) and [1056,2081)

    const float*  win  = ws;
    const float2* tw   = (const float2*)((const char*)ws + WS_TW);
    const int*    wbeg = (const int*)((const char*)ws + WS_WBEG);
    const float*  wtab = (const float*)((const char*)ws + WS_WTAB);

    const int tid = threadIdx.x;
    const int bid = blockIdx.x;
    const int b   = bid & 7;          // XCD-contiguous: one batch item per XCD
    const int t   = bid >> 3;

    const float2* xb = (const float2*)x + (size_t)b * S_LEN;
    const int tb = t*HOP - (N_FFT/2);

    float2 r[8], bq[8], w8[8];
    const int rb = tid + 2*(tid>>4);   // OFF(tid): read base, stride 288 per k

    // ---- Input: r[k] = z[tid + 256k] windowed; interior fast-path (99.7% of blocks).
    if (tb >= 0 && tb + (N_FFT - 1) < S_LEN) {
        #pragma unroll
        for (int k = 0; k < 8; ++k) {
            int n = tid + 256*k;
            float2 v = xb[tb + n];
            float  w = win[n];
            r[k] = make_float2(v.x*w, v.y*w);
        }
    } else {
        #pragma unroll
        for (int k = 0; k < 8; ++k) {
            int n  = tid + 256*k;
            int s0 = tb + n;
            if (s0 < 0) s0 = -s0; else if (s0 >= S_LEN) s0 = 2*S_LEN - 2 - s0;
            float2 v = xb[s0];
            float  w = win[n];
            r[k] = make_float2(v.x*w, v.y*w);
        }
    }

    // ======== Stage 1: radix-8, s=1. Outputs e = 8*tid + k (contiguous -> b128).
    bfly8(r, bq);
    twiddle8(bq, tw[tid], w8);
    {
        if (tid < 128) {
            int f4 = 4*tid + (tid>>1);
            #pragma unroll
            for (int j = 0; j < 4; ++j)
                Zq[f4+j] = make_float4(w8[2*j].x, w8[2*j].y, w8[2*j+1].x, w8[2*j+1].y);
        }
        __syncthreads();
        r[0]=Z[rb]; r[1]=Z[rb+288]; r[2]=Z[rb+576]; r[3]=Z[rb+864];
        __syncthreads();
        if (tid >= 128) {
            int tt = tid - 128;
            int f4 = 4*tt + (tt>>1);
            #pragma unroll
            for (int j = 0; j < 4; ++j)
                Zq[f4+j] = make_float4(w8[2*j].x, w8[2*j].y, w8[2*j+1].x, w8[2*j+1].y);
        }
        __syncthreads();
        r[4]=Z[rb]; r[5]=Z[rb+288]; r[6]=Z[rb+576]; r[7]=Z[rb+864];
        __syncthreads();
    }

    // ======== Stage 2: radix-8, s=8. Outputs e = q + 64a + 8k (q=tid&7, a=tid>>3).
    bfly8(r, bq);
    twiddle8(bq, tw[tid & ~7], w8);
    {
        int q = tid & 7, a = tid >> 3;
        if (tid < 128) {
            int base = q + 72*a;
            #pragma unroll
            for (int k = 0; k < 8; ++k) Z[base + 8*k + 2*(k>>1)] = w8[k];
        }
        __syncthreads();
        r[0]=Z[rb]; r[1]=Z[rb+288]; r[2]=Z[rb+576]; r[3]=Z[rb+864];
        __syncthreads();
        if (tid >= 128) {
            int base = q + 72*(a-16);
            #pragma unroll
            for (int k = 0; k < 8; ++k) Z[base + 8*k + 2*(k>>1)] = w8[k];
        }
        __syncthreads();
        r[4]=Z[rb]; r[5]=Z[rb+288]; r[6]=Z[rb+576]; r[7]=Z[rb+864];
        __syncthreads();
    }

    // ======== Stage 3: radix-8, s=64. Outputs e = q + 512a + 64k (q=tid&63, a=tid>>6).
    bfly8(r, bq);
    twiddle8(bq, tw[tid & ~63], w8);
    // Stage-4 butterfly pair: b1 = tid, b2 = 512-tid (tid=0 -> {0,256}).
    const int b1 = tid;
    const int b2 = (tid == 0) ? 256 : 512 - tid;
    const int rb1 = b1 + 2*(b1>>4);   // OFF(b1);  OFF(b1+512) = rb1+576
    const int rb2 = b2 + 2*(b2>>4);
    float2 A1[4], A2[4];
    {
        int q = tid & 63, a = tid >> 6;
        int qo = q + 2*(q>>4);
        if (tid < 128) {
            int base = qo + 576*a;                 // a in {0,1}
            #pragma unroll
            for (int k = 0; k < 8; ++k) Z[base + 72*k] = w8[k];
        }
        __syncthreads();
        A1[0]=Z[rb1]; A1[1]=Z[rb1+576]; A2[0]=Z[rb2]; A2[1]=Z[rb2+576];
        __syncthreads();
        if (tid >= 128) {
            int base = qo + 576*(a-2);             // a in {2,3}
            #pragma unroll
            for (int k = 0; k < 8; ++k) Z[base + 72*k] = w8[k];
        }
        __syncthreads();
        A1[2]=Z[rb1]; A1[3]=Z[rb1+576]; A2[2]=Z[rb2]; A2[3]=Z[rb2+576];
        __syncthreads();
    }

    // ======== Stage 4 (radix-4, s=512, twiddle-free) in registers.
    float2 O1[4], O2[4];
    {
        float2 apc=cadd(A1[0],A1[2]), amc=csub(A1[0],A1[2]);
        float2 bpd=cadd(A1[1],A1[3]), bmd=csub(A1[1],A1[3]);
        O1[0]=cadd(apc,bpd); O1[1]=cadd(amc,cnegi(bmd));
        O1[2]=csub(apc,bpd); O1[3]=csub(amc,cnegi(bmd));
    }
    {
        float2 apc=cadd(A2[0],A2[2]), amc=csub(A2[0],A2[2]);
        float2 bpd=cadd(A2[1],A2[3]), bmd=csub(A2[1],A2[3]);
        O2[0]=cadd(apc,bpd); O2[1]=cadd(amc,cnegi(bmd));
        O2[2]=csub(apc,bpd); O2[3]=csub(amc,cnegi(bmd));
    }

    // ======== Untangle in registers -> pw planes (aliases Z; reads fenced above).
    if (tid == 0) {
        float2 p;
        p = upair(O1[0], O1[0]); pwf[0]    = p.x; pwf[PW_OFF+0]    = p.y;
        p = upair(O1[1], O1[3]); pwf[512]  = p.x; pwf[PW_OFF+512]  = p.y;
        p = upair(O1[2], O1[2]); pwf[1024] = p.x; pwf[PW_OFF+1024] = p.y;
        p = upair(O2[0], O2[3]); pwf[256]  = p.x; pwf[PW_OFF+256]  = p.y;
        p = upair(O2[1], O2[2]); pwf[768]  = p.x; pwf[PW_OFF+768]  = p.y;
    } else {
        float2 p;
        p = upair(O1[0], O2[3]); pwf[tid]      = p.x; pwf[PW_OFF+tid]      = p.y;
        p = upair(O1[1], O2[2]); pwf[tid+512]  = p.x; pwf[PW_OFF+tid+512]  = p.y;
        p = upair(O2[0], O1[3]); pwf[512-tid]  = p.x; pwf[PW_OFF+512-tid]  = p.y;
        p = upair(O2[1], O1[2]); pwf[1024-tid] = p.x; pwf[PW_OFF+1024-tid] = p.y;
    }
    __syncthreads();

    // ======== Mel projection: (m,c) = (tid>>1, tid&1); fixed 16x float4, no
    // divergence (weights zero-padded to 64 taps, 4-aligned start).
    {
        int m = tid >> 1;
        int c = tid & 1;
        int a0 = wbeg[m];
        const float4* wt4 = (const float4*)(wtab + (m << 6));
        const float*  pwc = pwf + c * PW_OFF + a0;     // 16B-aligned
        float acc = 0.0f;
        #pragma unroll
        for (int j = 0; j < 16; ++j) {
            float4 w4 = wt4[j];
            float4 p4 = *(const float4*)(pwc + 4*j);
            acc += w4.x*p4.x + w4.y*p4.y + w4.z*p4.z + w4.w*p4.w;
        }
        out[(((size_t)b * N_MELS + m) * T_FRAMES + t) * CH + c] = acc;
    }
}

extern "C" void kernel_launch(void* const* d_in, const int* in_sizes, int n_in,
                              void* d_out, int out_size, void* d_ws, size_t ws_size,
                              hipStream_t stream) {
    const float* x  = (const float*)d_in[0];
    const float* fb = (const float*)d_in[1];
    float* out = (float*)d_out;
    float* ws  = (float*)d_ws;

    setup_kernel<<<8 + N_MELS, 256, 0, stream>>>(fb, ws);
    mel_spec_kernel<<<BATCH * T_FRAMES, 256, 0, stream>>>(x, fb, ws, out);
}

// Round 12
// 120.608 us; speedup vs baseline: 1.4345x; 1.2722x over previous
//
#include <hip/hip_runtime.h>
#include <math.h>

#define N_MELS   128
#define N_FFT    2048
#define HOP      512
#define BATCH    8
#define S_LEN    661500
#define CH       2
#define T_FRAMES 1292            // 1 + S_LEN/HOP
#define NBINS    1025            // 1 + N_FFT/2

#define ANG 0.003067961575771282f   // 2*pi/2048

// d_ws layout (byte offsets)
#define WS_WIN     0        // float[2048]   hann window
#define WS_TW      8192     // float2[2048]  W_2048^j
#define WS_WBEG    24576    // int[128]      4-aligned start bin per mel
#define WS_WTAB    25600    // float[128*64] dense zero-padded mel weights

#define PW_OFF   1056       // channel-plane stride (floats)
#define PW_FR    2112       // frame-plane stride (floats)

// Full padded buffer: element e in [0,2048) lives at Z2[e + 2*(e>>4)].
#define ZN 2304             // float2 count = 2048 + 2*128 -> 18432 B

__device__ __forceinline__ float2 cadd(float2 a, float2 b){ return make_float2(a.x+b.x, a.y+b.y); }
__device__ __forceinline__ float2 csub(float2 a, float2 b){ return make_float2(a.x-b.x, a.y-b.y); }
__device__ __forceinline__ float2 cmul(float2 a, float2 b){ return make_float2(a.x*b.x - a.y*b.y, a.x*b.y + a.y*b.x); }
__device__ __forceinline__ float2 cnegi(float2 z){ return make_float2(z.y, -z.x); }   // -i*z

// radix-8 DIF butterfly: b[k] = sum_j a[j] * W8^{jk}, W8 = exp(-i*pi/4)
__device__ __forceinline__ void bfly8(const float2* a, float2* b) {
    const float C = 0.70710678118654752f;
    float2 e0=cadd(a[0],a[4]), e1=cadd(a[1],a[5]), e2=cadd(a[2],a[6]), e3=cadd(a[3],a[7]);
    float2 o0=csub(a[0],a[4]), o1=csub(a[1],a[5]), o2=csub(a[2],a[6]), o3=csub(a[3],a[7]);
    float2 t1 = make_float2(C*(o1.x+o1.y), C*(o1.y-o1.x));      // o1*W8^1
    float2 t2 = make_float2(o2.y, -o2.x);                        // o2*W8^2 (-i)
    float2 t3 = make_float2(C*(o3.y-o3.x), -C*(o3.x+o3.y));      // o3*W8^3
    {
        float2 s0=cadd(e0,e2), d0=csub(e0,e2);
        float2 s1=cadd(e1,e3), d1=csub(e1,e3);
        b[0]=cadd(s0,s1); b[4]=csub(s0,s1);
        b[2]=cadd(d0,cnegi(d1)); b[6]=csub(d0,cnegi(d1));
    }
    {
        float2 s0=cadd(o0,t2), d0=csub(o0,t2);
        float2 s1=cadd(t1,t3), d1=csub(t1,t3);
        b[1]=cadd(s0,s1); b[5]=csub(s0,s1);
        b[3]=cadd(d0,cnegi(d1)); b[7]=csub(d0,cnegi(d1));
    }
}

// Both frames: bfly8 + shared incremental twiddle chain, results back into rA/rB.
__device__ __forceinline__ void stage_pair(float2* rA, float2* rB, float2 w1) {
    float2 bqA[8], bqB[8];
    bfly8(rA, bqA);
    bfly8(rB, bqB);
    rA[0] = bqA[0]; rB[0] = bqB[0];
    float2 wk = w1;
    #pragma unroll
    for (int k = 1; k < 8; ++k) {
        rA[k] = cmul(wk, bqA[k]);
        rB[k] = cmul(wk, bqB[k]);
        wk = cmul(wk, w1);
    }
}

// stage-4 radix-4 (s=512, twiddle-free) butterfly
__device__ __forceinline__ void bf4(const float2* I, float2* O) {
    float2 apc=cadd(I[0],I[2]), amc=csub(I[0],I[2]);
    float2 bpd=cadd(I[1],I[3]), bmd=csub(I[1],I[3]);
    O[0]=cadd(apc,bpd); O[1]=cadd(amc,cnegi(bmd));
    O[2]=csub(apc,bpd); O[3]=csub(amc,cnegi(bmd));
}

// two-channel untangle: (|A|^2, |B|^2) for Zf, Zm = Z[N-f]
__device__ __forceinline__ float2 upair(float2 Zf, float2 Zm) {
    float br = Zm.x, bi = -Zm.y;
    float e0 = Zf.x + br, e1 = Zf.y + bi;
    float o0 = Zf.y - bi, o1 = Zf.x - br;
    return make_float2(0.25f*(e0*e0 + e1*e1), 0.25f*(o0*o0 + o1*o1));
}

// --- setup: blocks 0..7 build tables; blocks 8..135: mel weight rows ---
__global__ __launch_bounds__(256) void setup_kernel(
        const float* __restrict__ fb, float* __restrict__ ws) {
    int blk = blockIdx.x;
    if (blk < 8) {
        int i = blk * 256 + threadIdx.x;
        float*  win = ws;
        float2* tw  = (float2*)((char*)ws + WS_TW);
        win[i] = 0.5f - 0.5f * cosf(ANG * (float)i);
        float sn, cs; sincosf(-ANG * (float)i, &sn, &cs);
        tw[i] = make_float2(cs, sn);
    } else {
        int m = blk - 8;
        int lane = threadIdx.x;
        if (lane < 64) {
            int*   wbeg = (int*)((char*)ws + WS_WBEG);
            float* wtab = (float*)((char*)ws + WS_WTAB);
            const float* row = fb + m * NBINS;
            int s = NBINS;
            for (int f = lane; f < NBINS; f += 64)
                if (row[f] != 0.0f && f < s) s = f;
            #pragma unroll
            for (int o = 32; o; o >>= 1) s = min(s, __shfl_xor(s, o));
            int a0 = s & ~3;              // 4-aligned start; slaney span<=54+3<64
            if (a0 > NBINS - 1) a0 = (NBINS - 1) & ~3;
            if (lane == 0) wbeg[m] = a0;
            int f = a0 + lane;
            wtab[(m << 6) + lane] = (f < NBINS) ? row[f] : 0.0f;
        }
    }
}

// --- main: 2 frames per block; full-buffer exchange, frames alternate ---
__global__ __launch_bounds__(256, 4) void mel_spec_kernel(
        const float* __restrict__ x, const float* __restrict__ fb,
        const float* __restrict__ ws, float* __restrict__ out) {
    __shared__ float4 Zq[ZN/2];          // 18432 B, one full padded buffer
    float2* Z2  = (float2*)Zq;
    float*  pwb = (float*)Zq;            // pw planes: [h*2112 + c*1056 + f]

    const float*  win  = ws;
    const float2* tw   = (const float2*)((const char*)ws + WS_TW);
    const int*    wbeg = (const int*)((const char*)ws + WS_WBEG);
    const float*  wtab = (const float*)((const char*)ws + WS_WTAB);

    const int tid = threadIdx.x;
    const int bid = blockIdx.x;
    const int b   = bid & 7;              // XCD-contiguous: one batch item per XCD
    const int t0  = (bid >> 3) * 2;       // frames t0, t0+1

    const float2* xb = (const float2*)x + (size_t)b * S_LEN;
    const int tbA = t0*HOP - (N_FFT/2);
    const int tbB = tbA + HOP;

    float2 rA[8], rB[8];
    const int rb = tid + 2*(tid>>4);      // OFFE(tid); +288 per 256 elements

    // ---- Input: per-frame loads, uniform fast/slow branch.
    if (tbA >= 0 && tbB + (N_FFT - 1) < S_LEN) {
        #pragma unroll
        for (int k = 0; k < 8; ++k) {
            int n = tid + 256*k;
            float w = win[n];
            float2 vA = xb[tbA + n];
            float2 vB = xb[tbB + n];
            rA[k] = make_float2(vA.x*w, vA.y*w);
            rB[k] = make_float2(vB.x*w, vB.y*w);
        }
    } else {
        #pragma unroll
        for (int k = 0; k < 8; ++k) {
            int n  = tid + 256*k;
            float w = win[n];
            int sA = tbA + n;
            if (sA < 0) sA = -sA; else if (sA >= S_LEN) sA = 2*S_LEN - 2 - sA;
            float2 vA = xb[sA];
            rA[k] = make_float2(vA.x*w, vA.y*w);
            int sB = tbB + n;
            if (sB < 0) sB = -sB; else if (sB >= S_LEN) sB = 2*S_LEN - 2 - sB;
            float2 vB = xb[sB];
            rB[k] = make_float2(vB.x*w, vB.y*w);
        }
    }

    // ======== Stage 1: radix-8, s=1. Outputs e = 8*tid + k (b128 writes).
    stage_pair(rA, rB, tw[tid]);
    {
        const int f4 = 4*tid + (tid>>1);          // float4 index of OFFE(8*tid)/2
        #pragma unroll
        for (int j = 0; j < 4; ++j)
            Zq[f4+j] = make_float4(rA[2*j].x, rA[2*j].y, rA[2*j+1].x, rA[2*j+1].y);
        __syncthreads();
        #pragma unroll
        for (int k = 0; k < 8; ++k) rA[k] = Z2[rb + 288*k];
        __syncthreads();
        #pragma unroll
        for (int j = 0; j < 4; ++j)
            Zq[f4+j] = make_float4(rB[2*j].x, rB[2*j].y, rB[2*j+1].x, rB[2*j+1].y);
        __syncthreads();
        #pragma unroll
        for (int k = 0; k < 8; ++k) rB[k] = Z2[rb + 288*k];
        __syncthreads();
    }

    // ======== Stage 2: radix-8, s=8. Outputs e = q + 64a + 8k.
    stage_pair(rA, rB, tw[tid & ~7]);
    {
        const int base = (tid & 7) + 72*(tid >> 3);
        #pragma unroll
        for (int k = 0; k < 8; ++k) Z2[base + 8*k + 2*(k>>1)] = rA[k];
        __syncthreads();
        #pragma unroll
        for (int k = 0; k < 8; ++k) rA[k] = Z2[rb + 288*k];
        __syncthreads();
        #pragma unroll
        for (int k = 0; k < 8; ++k) Z2[base + 8*k + 2*(k>>1)] = rB[k];
        __syncthreads();
        #pragma unroll
        for (int k = 0; k < 8; ++k) rB[k] = Z2[rb + 288*k];
        __syncthreads();
    }

    // ======== Stage 3: radix-8, s=64. Outputs e = q + 512a + 64k.
    stage_pair(rA, rB, tw[tid & ~63]);
    // Stage-4 butterfly pair: b1 = tid, b2 = 512-tid (tid=0 -> {0,256}).
    const int b2  = (tid == 0) ? 256 : 512 - tid;
    const int rb2 = b2 + 2*(b2>>4);
    float2 A1[4], A2[4], B1[4], B2[4];
    {
        const int q = tid & 63;
        const int base = q + 2*(q>>4) + 576*(tid >> 6);
        #pragma unroll
        for (int k = 0; k < 8; ++k) Z2[base + 72*k] = rA[k];
        __syncthreads();
        #pragma unroll
        for (int k = 0; k < 4; ++k) { A1[k] = Z2[rb + 576*k]; A2[k] = Z2[rb2 + 576*k]; }
        __syncthreads();
        #pragma unroll
        for (int k = 0; k < 8; ++k) Z2[base + 72*k] = rB[k];
        __syncthreads();
        #pragma unroll
        for (int k = 0; k < 4; ++k) { B1[k] = Z2[rb + 576*k]; B2[k] = Z2[rb2 + 576*k]; }
        __syncthreads();
    }

    // ======== Stage 4 + untangle, straight-line per frame (registers only,
    // then pw-plane writes into Zq; all Zq reads fenced above).
    {
        float2 O1[4], O2[4];
        bf4(A1, O1); bf4(A2, O2);
        float* pwf = pwb;                          // frame A planes (h=0)
        if (tid == 0) {
            float2 p;
            p = upair(O1[0], O1[0]); pwf[0]    = p.x; pwf[PW_OFF+0]    = p.y;
            p = upair(O1[1], O1[3]); pwf[512]  = p.x; pwf[PW_OFF+512]  = p.y;
            p = upair(O1[2], O1[2]); pwf[1024] = p.x; pwf[PW_OFF+1024] = p.y;
            p = upair(O2[0], O2[3]); pwf[256]  = p.x; pwf[PW_OFF+256]  = p.y;
            p = upair(O2[1], O2[2]); pwf[768]  = p.x; pwf[PW_OFF+768]  = p.y;
        } else {
            float2 p;
            p = upair(O1[0], O2[3]); pwf[tid]      = p.x; pwf[PW_OFF+tid]      = p.y;
            p = upair(O1[1], O2[2]); pwf[tid+512]  = p.x; pwf[PW_OFF+tid+512]  = p.y;
            p = upair(O2[0], O1[3]); pwf[512-tid]  = p.x; pwf[PW_OFF+512-tid]  = p.y;
            p = upair(O2[1], O1[2]); pwf[1024-tid] = p.x; pwf[PW_OFF+1024-tid] = p.y;
        }
    }
    {
        float2 O1[4], O2[4];
        bf4(B1, O1); bf4(B2, O2);
        float* pwf = pwb + PW_FR;                  // frame B planes (h=1)
        if (tid == 0) {
            float2 p;
            p = upair(O1[0], O1[0]); pwf[0]    = p.x; pwf[PW_OFF+0]    = p.y;
            p = upair(O1[1], O1[3]); pwf[512]  = p.x; pwf[PW_OFF+512]  = p.y;
            p = upair(O1[2], O1[2]); pwf[1024] = p.x; pwf[PW_OFF+1024] = p.y;
            p = upair(O2[0], O2[3]); pwf[256]  = p.x; pwf[PW_OFF+256]  = p.y;
            p = upair(O2[1], O2[2]); pwf[768]  = p.x; pwf[PW_OFF+768]  = p.y;
        } else {
            float2 p;
            p = upair(O1[0], O2[3]); pwf[tid]      = p.x; pwf[PW_OFF+tid]      = p.y;
            p = upair(O1[1], O2[2]); pwf[tid+512]  = p.x; pwf[PW_OFF+tid+512]  = p.y;
            p = upair(O2[0], O1[3]); pwf[512-tid]  = p.x; pwf[PW_OFF+512-tid]  = p.y;
            p = upair(O2[1], O1[2]); pwf[1024-tid] = p.x; pwf[PW_OFF+1024-tid] = p.y;
        }
    }
    __syncthreads();

    // ======== Mel projection: thread = (m, frame h); both channels -> float2 out.
    // No clamp on a0: wtab is aligned to the SAME a0 (R11's clamp desynced
    // them for m=127, a0=972). Reads past bin 1024 hit zero weights and
    // finite in-buffer leftovers -> contribute exactly 0.
    {
        int m = tid >> 1;
        int h = tid & 1;                       // frame t0+h
        int a0 = wbeg[m];
        const float4* wt4 = (const float4*)(wtab + (m << 6));
        const float*  p0  = pwb + h*PW_FR + a0;            // channel 0 plane
        const float*  p1  = pwb + h*PW_FR + PW_OFF + a0;   // channel 1 plane
        float acc0 = 0.0f, acc1 = 0.0f;
        #pragma unroll
        for (int j = 0; j < 16; ++j) {
            float4 w4 = wt4[j];
            float4 q0 = *(const float4*)(p0 + 4*j);
            float4 q1 = *(const float4*)(p1 + 4*j);
            acc0 += w4.x*q0.x + w4.y*q0.y + w4.z*q0.z + w4.w*q0.w;
            acc1 += w4.x*q1.x + w4.y*q1.y + w4.z*q1.z + w4.w*q1.w;
        }
        size_t base = (((size_t)b * N_MELS + m) * T_FRAMES + t0 + h) * CH;
        *(float2*)(out + base) = make_float2(acc0, acc1);
    }
}

extern "C" void kernel_launch(void* const* d_in, const int* in_sizes, int n_in,
                              void* d_out, int out_size, void* d_ws, size_t ws_size,
                              hipStream_t stream) {
    const float* x  = (const float*)d_in[0];
    const float* fb = (const float*)d_in[1];
    float* out = (float*)d_out;
    float* ws  = (float*)d_ws;

    setup_kernel<<<8 + N_MELS, 256, 0, stream>>>(fb, ws);
    mel_spec_kernel<<<BATCH * (T_FRAMES/2), 256, 0, stream>>>(x, fb, ws, out);
}